// Round 11
// baseline (498.661 us; speedup 1.0000x reference)
//
#include <hip/hip_runtime.h>

#define K_CLUSTERS 512
#define FDIM 64
#define RPB 512      // rows per block; grid = N/RPB = 256 (1 block/CU)
#define RT 8         // rows per wave-tile
#define NTILES 4     // tiles per wave: RPB / (16 waves * RT)
#define WSTRIDE 17   // vf4 per LDS W row (16 + 1 pad -> conflict-free b128 reads)

typedef float vf4 __attribute__((ext_vector_type(4)));

// Transpose W [F=64][K=512] -> Wt [K][F] (for epilogue gather), wsq[k].
// UNCHANGED (absmax 0.0 proven).
__global__ __launch_bounds__(64) void vq_prep(const float* __restrict__ W,
                                              float* __restrict__ Wt,
                                              float* __restrict__ wsq) {
    int k = blockIdx.x;
    int f = threadIdx.x;
    float w = W[f * K_CLUSTERS + k];
    Wt[k * FDIM + f] = w;
    float s = w * w;
#pragma unroll
    for (int off = 32; off > 0; off >>= 1) s += __shfl_xor(s, off, 64);
    if (f == 0) wsq[k] = s;
}

// Fused argmin + zq + diff + one-hot.
// Round-11 == round-10 resubmitted (round-10 bench died to a container-acquire
// infra failure; kernel never ran).
// Rationale: r6-r9 post-mortems excluded broadcast count (r7 null), occupancy
// (r8 null) and store interleave (r9 split, compute alone ~150 us); the
// survivor is the per-f4 lgkmcnt(0) drain forced by mixing ds_read (in-order)
// with s_load z broadcasts (OOO SMEM) in one counter domain. Fix: z tile
// lives in REGISTERS (zreg[r] = z[row0+r][lane], 8 VGPRs) and the broadcast
// is v_readlane (pure VALU, uniform constant lane index 4*f4+m). The only
// hot-loop memory ops are the 4 wv ds_read_b128, prefetched one f4 ahead ->
// compiler can emit counted lgkmcnt and the LDS latency hides under the
// previous iteration's 320-cycle fmaf block.
// All arithmetic chains bit-identical to the proven kernels (absmax 0.0):
// readlane yields the same z bits in the same m=0..3 ascending order as the
// proven zb.x/y/z/w chain; ascending-f single-acc fmaf dot; fmaf(-2,dot,s)
// +wsq; 8-lane sumz + shfl_xor tree (proven r3/5/6/7); jj ascending == c
// ascending strict-< lex-min == np.argmin first-index; contract-off epilogue.
__global__ __launch_bounds__(1024)
__attribute__((amdgpu_waves_per_eu(4, 4)))
void vq_fused(const float* __restrict__ z,
              const float* __restrict__ W,
              const float* __restrict__ Wt,
              const float* __restrict__ wsq,
              float* __restrict__ out_zq,
              float* __restrict__ out_idx,
              float* __restrict__ enc,
              float* __restrict__ out_diff) {
    __shared__ vf4 sW4[K_CLUSTERS * WSTRIDE];   // 136 KB, the only LDS

    const int tid = threadIdx.x;
    const int w = __builtin_amdgcn_readfirstlane(tid) >> 6;  // uniform wave id
    const int l = tid & 63;

    // ---- Stage W into LDS (coalesced vf4 reads, strided scalar writes) ----
    {
        float* sWf = (float*)sW4;
        const vf4* Wg4 = (const vf4*)W;
#pragma unroll
        for (int it = 0; it < 8; it++) {
            int u4 = it * 1024 + tid;       // vf4 index over W (8192 total)
            vf4 v = Wg4[u4];
            int u = u4 << 2;                // float index; 4 elems same f, c0..c0+3
            int f = u >> 9;
            int c0 = u & 511;
            int f4 = f >> 2, m = f & 3;
#pragma unroll
            for (int e = 0; e < 4; e++) {
                int c = c0 + e;
                sWf[c * (4 * WSTRIDE) + (f4 << 2) + m] = v[e];
            }
        }
    }
    __syncthreads();  // the only barrier in the kernel

    const int rowW = blockIdx.x * RPB + w * (RT * NTILES);
    const vf4* zg4 = (const vf4*)z;

    // ---- per-lane z rows for the first tile: zreg[r] = z[row0+r][lane] ----
    float zreg[RT];
#pragma unroll
    for (int r = 0; r < RT; r++) zreg[r] = z[(size_t)(rowW + r) * FDIM + l];

#pragma unroll 1
    for (int t = 0; t < NTILES; t++) {
        const int row0 = rowW + t * RT;     // wave-uniform (SGPR)

        // prefetch next tile's z rows early (hides under this tile's compute)
        float zregN[RT];
        {
            const int rows_next = (t < NTILES - 1) ? row0 + RT : row0;
#pragma unroll
            for (int r = 0; r < RT; r++)
                zregN[r] = z[(size_t)(rows_next + r) * FDIM + l];
        }

        // ---- sumz: 8 lanes per row, one exact accumulator chain per lane ----
        float srow;
        {
            const float* zr = z + (size_t)(row0 + (l >> 3)) * FDIM;
            const int j = l & 7;
            float rj;
            {
#pragma clang fp contract(off)
                rj = zr[j] * zr[j];
#pragma unroll
                for (int b = 8; b < 64; b += 8) rj += zr[b + j] * zr[b + j];
            }
            float s01 = rj + __shfl_xor(rj, 1, 64);
            float s03 = s01 + __shfl_xor(s01, 2, 64);
            srow = s03 + __shfl_xor(s03, 4, 64);
        }
        float sA[RT];
#pragma unroll
        for (int r = 0; r < RT; r++) sA[r] = __shfl(srow, r << 3, 64);

        float bd[RT];
        int bk[RT];
#pragma unroll
        for (int r = 0; r < RT; r++) { bd[r] = INFINITY; bk[r] = 0; }

        // ---- two passes: lane l owns c = pass*256 + jj*64 + l, jj=0..3 ----
#pragma unroll 1
        for (int pass = 0; pass < 2; pass++) {
            const int cBase = (pass << 8) + l;
            float acc[RT][4];
#pragma unroll
            for (int r = 0; r < RT; r++)
#pragma unroll
                for (int jj = 0; jj < 4; jj++) acc[r][jj] = 0.0f;

            const vf4* wP = sW4 + (size_t)cBase * WSTRIDE;
            // prologue: wv for f4 = 0
            vf4 w0 = wP[0];
            vf4 w1 = wP[64 * WSTRIDE];
            vf4 w2 = wP[128 * WSTRIDE];
            vf4 w3 = wP[192 * WSTRIDE];

#pragma unroll 2
            for (int f4 = 0; f4 < 16; f4++) {
                // prefetch next wv (ds, in-order -> counted lgkmcnt; wraps
                // harmlessly to 0 on the last iteration)
                const int fp = (f4 + 1) & 15;
                vf4 n0 = wP[fp];
                vf4 n1 = wP[64 * WSTRIDE + fp];
                vf4 n2 = wP[128 * WSTRIDE + fp];
                vf4 n3 = wP[192 * WSTRIDE + fp];
#pragma unroll
                for (int r = 0; r < RT; r++) {
                    // z broadcast from registers: pure VALU, no memory op.
                    // Same bits, same m=0..3 ascending order as proven chain.
                    float zx = __int_as_float(__builtin_amdgcn_readlane(
                        __float_as_int(zreg[r]), (f4 << 2) + 0));
                    float zy = __int_as_float(__builtin_amdgcn_readlane(
                        __float_as_int(zreg[r]), (f4 << 2) + 1));
                    float zz = __int_as_float(__builtin_amdgcn_readlane(
                        __float_as_int(zreg[r]), (f4 << 2) + 2));
                    float zw = __int_as_float(__builtin_amdgcn_readlane(
                        __float_as_int(zreg[r]), (f4 << 2) + 3));
                    float a0 = acc[r][0], a1 = acc[r][1], a2 = acc[r][2], a3 = acc[r][3];
                    a0 = fmaf(zx, w0.x, a0); a1 = fmaf(zx, w1.x, a1);
                    a2 = fmaf(zx, w2.x, a2); a3 = fmaf(zx, w3.x, a3);
                    a0 = fmaf(zy, w0.y, a0); a1 = fmaf(zy, w1.y, a1);
                    a2 = fmaf(zy, w2.y, a2); a3 = fmaf(zy, w3.y, a3);
                    a0 = fmaf(zz, w0.z, a0); a1 = fmaf(zz, w1.z, a1);
                    a2 = fmaf(zz, w2.z, a2); a3 = fmaf(zz, w3.z, a3);
                    a0 = fmaf(zw, w0.w, a0); a1 = fmaf(zw, w1.w, a1);
                    a2 = fmaf(zw, w2.w, a2); a3 = fmaf(zw, w3.w, a3);
                    acc[r][0] = a0; acc[r][1] = a1; acc[r][2] = a2; acc[r][3] = a3;
                }
                w0 = n0; w1 = n1; w2 = n2; w3 = n3;
            }

            // distances + thread-local lex-min (jj ascending == c ascending)
            const float q0 = wsq[cBase];
            const float q1 = wsq[cBase + 64];
            const float q2 = wsq[cBase + 128];
            const float q3 = wsq[cBase + 192];
#pragma unroll
            for (int r = 0; r < RT; r++) {
                float d0 = fmaf(-2.0f, acc[r][0], sA[r]) + q0;
                float d1 = fmaf(-2.0f, acc[r][1], sA[r]) + q1;
                float d2 = fmaf(-2.0f, acc[r][2], sA[r]) + q2;
                float d3 = fmaf(-2.0f, acc[r][3], sA[r]) + q3;
                if (d0 < bd[r] || (d0 == bd[r] && cBase < bk[r])) { bd[r] = d0; bk[r] = cBase; }
                if (d1 < bd[r] || (d1 == bd[r] && cBase + 64 < bk[r])) { bd[r] = d1; bk[r] = cBase + 64; }
                if (d2 < bd[r] || (d2 == bd[r] && cBase + 128 < bk[r])) { bd[r] = d2; bk[r] = cBase + 128; }
                if (d3 < bd[r] || (d3 == bd[r] && cBase + 192 < bk[r])) { bd[r] = d3; bk[r] = cBase + 192; }
            }
        }

        // ---- 64-lane butterfly lex-min; 8 independent row-chains interleave ----
#pragma unroll
        for (int off = 1; off < 64; off <<= 1) {
#pragma unroll
            for (int r = 0; r < RT; r++) {
                float od = __shfl_xor(bd[r], off, 64);
                int ok = __shfl_xor(bk[r], off, 64);
                if (od < bd[r] || (od == bd[r] && ok < bk[r])) { bd[r] = od; bk[r] = ok; }
            }
        }
        // all lanes now hold the final (bd,bk) for all 8 rows

        if (l == 0) {
#pragma unroll
            for (int r = 0; r < RT; r++) out_idx[row0 + r] = (float)bk[r];
        }

        // ---- zq & diff (z re-read per-lane from L1/L2, w gather from Wt) ----
        const vf4* ztv = zg4 + (size_t)row0 * 16;
#pragma unroll
        for (int h = 0; h < 2; h++) {
            const int rsel = l >> 4;              // 0..3 within half
            int kk = bk[4 * h + 0];
            if (rsel == 1) kk = bk[4 * h + 1];
            if (rsel == 2) kk = bk[4 * h + 2];
            if (rsel == 3) kk = bk[4 * h + 3];
            vf4 zvv = ztv[(h << 6) + l];          // == z[row0 + 4h + rsel][chunk]
            vf4 wvv = ((const vf4*)Wt)[((size_t)kk << 4) + (l & 15)];
            vf4 zq, df;
            {
#pragma clang fp contract(off)
                vf4 d1 = wvv - zvv;
                zq = zvv + d1;
                df = d1 * d1;
            }
            ((vf4*)out_zq)[(size_t)row0 * 16 + (h << 6) + l] = zq;
            ((vf4*)out_diff)[(size_t)row0 * 16 + (h << 6) + l] = df;
        }

        // ---- one-hot: coalesced plain stores, 16 x 1KB per wave-tile ----
        {
            vf4* enc4 = (vf4*)enc + (size_t)row0 * 128;
#pragma unroll
            for (int jj = 0; jj < 16; jj++) {
                const int row = jj >> 1;     // compile-time per unrolled jj
                int kk = bk[row];
                int c = kk - ((l + ((jj & 1) << 6)) << 2);
                vf4 v;
                v.x = (c == 0) ? 1.0f : 0.0f;
                v.y = (c == 1) ? 1.0f : 0.0f;
                v.z = (c == 2) ? 1.0f : 0.0f;
                v.w = (c == 3) ? 1.0f : 0.0f;
                enc4[(jj << 6) + l] = v;
            }
        }

        // rotate prefetched z rows into place
#pragma unroll
        for (int r = 0; r < RT; r++) zreg[r] = zregN[r];
    }
}

extern "C" void kernel_launch(void* const* d_in, const int* in_sizes, int n_in,
                              void* d_out, int out_size, void* d_ws, size_t ws_size,
                              hipStream_t stream) {
    const float* z = (const float*)d_in[0];
    const float* W = (const float*)d_in[1];
    int N = in_sizes[0] / FDIM;  // 131072

    float* out = (float*)d_out;
    float* out_zq = out;
    float* out_idx = out_zq + (size_t)N * FDIM;
    float* enc = out_idx + N;
    float* out_diff = enc + (size_t)N * K_CLUSTERS;

    float* Wt = (float*)d_ws;
    float* wsq = Wt + K_CLUSTERS * FDIM;

    vq_prep<<<K_CLUSTERS, 64, 0, stream>>>(W, Wt, wsq);
    vq_fused<<<N / RPB, 1024, 0, stream>>>(z, W, Wt, wsq, out_zq, out_idx, enc, out_diff);
}